// Round 1
// baseline (384.964 us; speedup 1.0000x reference)
//
#include <hip/hip_runtime.h>
#include <hip/hip_bf16.h>
#include <stdint.h>

typedef __attribute__((ext_vector_type(8))) short bf16x8;
typedef __attribute__((ext_vector_type(4))) float f32x4;

__device__ __forceinline__ unsigned short f2bf(float f) {
  union { float f; unsigned int u; } v; v.f = f;
  unsigned int u = v.u;
  u += 0x7fffu + ((u >> 16) & 1u);
  return (unsigned short)(u >> 16);
}

// ---------- X transform: [512,256,20,20] f32 -> Xt [512,400,256] bf16 ----------
__global__ __launch_bounds__(256) void xform_x(const float* __restrict__ X,
                                               unsigned short* __restrict__ Xt) {
  const int b = blockIdx.x;
  const int t = threadIdx.x;  // = ci
  const float* src = X + ((size_t)b * 256 + t) * 400;
  unsigned short* dst = Xt + (size_t)b * 400 * 256 + t;
  for (int hw = 0; hw < 400; hw += 4) {
    float4 v = *(const float4*)(src + hw);
    dst[(size_t)(hw + 0) * 256] = f2bf(v.x);
    dst[(size_t)(hw + 1) * 256] = f2bf(v.y);
    dst[(size_t)(hw + 2) * 256] = f2bf(v.z);
    dst[(size_t)(hw + 3) * 256] = f2bf(v.w);
  }
}

// ---------- W transform: [256co][256ci][81] f32 -> Wt [81][256co][256ci] bf16 ----------
__global__ __launch_bounds__(256) void xform_w(const float* __restrict__ W,
                                               unsigned short* __restrict__ Wt) {
  __shared__ unsigned short lds[81 * 128];
  const int co = blockIdx.x;       // 0..255
  const int ct = blockIdx.y;       // 0..1 (ci tile of 128)
  const int t = threadIdx.x;
  const float* src = W + ((size_t)co * 256 + (size_t)ct * 128) * 81;
  for (int idx = t; idx < 128 * 81; idx += 256) {
    int ci_l = idx / 81, khw = idx - ci_l * 81;
    lds[khw * 128 + ci_l] = f2bf(src[idx]);   // src read is fully linear
  }
  __syncthreads();
  unsigned short* dst = Wt + (size_t)co * 256 + (size_t)ct * 128;
  for (int idx = t; idx < 81 * 128; idx += 256) {
    int khw = idx >> 7, ci_l = idx & 127;
    dst[(size_t)khw * 65536 + ci_l] = lds[idx];  // coalesced 128-elem rows
  }
}

// ---------- implicit-GEMM conv + bias ----------
// M = 18432 (b,oh,ow), N = 256 (co), K = 81*256 in order (kh,kw,ci)
// BM=128 BN=64 BK=64, 4 waves (2x2), mfma_f32_16x16x32_bf16
__device__ __forceinline__ void gload16(const unsigned short* g, unsigned short* l) {
  __builtin_amdgcn_global_load_lds(
      (const __attribute__((address_space(1))) unsigned int*)g,
      (__attribute__((address_space(3))) unsigned int*)l, 16, 0, 0);
}

__global__ __launch_bounds__(256, 2) void conv_gemm(
    const unsigned short* __restrict__ Xt,
    const unsigned short* __restrict__ Wt,
    const float* __restrict__ bias,
    float* __restrict__ Y) {
  __shared__ unsigned short sA[128 * 64];  // swizzled [row][ci] bf16
  __shared__ unsigned short sB[64 * 64];   // swizzled [co][ci] bf16
  const int mt = blockIdx.x;   // 0..143
  const int nt = blockIdx.y;   // 0..3
  const int t = threadIdx.x;
  const int c8 = t & 7, rq = t >> 3;           // staging: 8 lanes per row, 32 rows/round
  const int swz = (c8 ^ (rq & 7)) * 8;         // pre-swizzled ci element offset

  // A staging row bases (rows r*32+rq, m = mt*128+row -> (b,oh,ow))
  int xb[4];
  #pragma unroll
  for (int r = 0; r < 4; ++r) {
    int m = mt * 128 + r * 32 + rq;
    int b = m / 36, s = m - b * 36;
    int oh = s / 6, ow = s - oh * 6;
    xb[r] = ((b * 20 + 2 * oh) * 20 + 2 * ow) * 256;
  }
  int wb[2];
  #pragma unroll
  for (int r = 0; r < 2; ++r) wb[r] = (nt * 64 + r * 32 + rq) * 256;

  unsigned short* ldsA = sA + t * 8;  // linear dest: byte = row*128 + c8*16
  unsigned short* ldsB = sB + t * 8;

  const int lane = t & 63, wv = t >> 6;
  const int wm = (wv >> 1) * 64, wn = (wv & 1) * 32;
  const int l15 = lane & 15, l4 = lane >> 4, l7 = lane & 7;

  // fragment LDS pointers (swizzle-matched reads, 2-way max conflict)
  const unsigned short* pA[4][2];
  const unsigned short* pB[2][2];
  #pragma unroll
  for (int i = 0; i < 4; ++i)
    #pragma unroll
    for (int kk = 0; kk < 2; ++kk)
      pA[i][kk] = sA + ((wm + i * 16 + l15) * 128 +
                        ((kk * 64 + l4 * 16) ^ (l7 << 4))) / 2;
  #pragma unroll
  for (int j = 0; j < 2; ++j)
    #pragma unroll
    for (int kk = 0; kk < 2; ++kk)
      pB[j][kk] = sB + ((wn + j * 16 + l15) * 128 +
                        ((kk * 64 + l4 * 16) ^ (l7 << 4))) / 2;

  f32x4 acc[4][2];
  #pragma unroll
  for (int i = 0; i < 4; ++i)
    #pragma unroll
    for (int j = 0; j < 2; ++j) acc[i][j] = (f32x4){0.f, 0.f, 0.f, 0.f};

  #pragma unroll 1
  for (int kh = 0; kh < 9; ++kh) {
    #pragma unroll 1
    for (int kw = 0; kw < 9; ++kw) {
      const unsigned short* xsrc = Xt + (kh * 20 + kw) * 256 + swz;
      const unsigned short* wsrc = Wt + (kh * 9 + kw) * 65536 + swz;
      for (int ci0 = 0; ci0 < 256; ci0 += 64) {
        gload16(xsrc + xb[0] + ci0, ldsA + 0 * 2048);
        gload16(xsrc + xb[1] + ci0, ldsA + 1 * 2048);
        gload16(xsrc + xb[2] + ci0, ldsA + 2 * 2048);
        gload16(xsrc + xb[3] + ci0, ldsA + 3 * 2048);
        gload16(wsrc + wb[0] + ci0, ldsB + 0 * 2048);
        gload16(wsrc + wb[1] + ci0, ldsB + 1 * 2048);
        __syncthreads();
        bf16x8 af[4][2], bfr[2][2];
        #pragma unroll
        for (int i = 0; i < 4; ++i)
          #pragma unroll
          for (int kk = 0; kk < 2; ++kk) af[i][kk] = *(const bf16x8*)pA[i][kk];
        #pragma unroll
        for (int j = 0; j < 2; ++j)
          #pragma unroll
          for (int kk = 0; kk < 2; ++kk) bfr[j][kk] = *(const bf16x8*)pB[j][kk];
        #pragma unroll
        for (int i = 0; i < 4; ++i)
          #pragma unroll
          for (int j = 0; j < 2; ++j) {
            acc[i][j] = __builtin_amdgcn_mfma_f32_16x16x32_bf16(
                af[i][0], bfr[j][0], acc[i][j], 0, 0, 0);
            acc[i][j] = __builtin_amdgcn_mfma_f32_16x16x32_bf16(
                af[i][1], bfr[j][1], acc[i][j], 0, 0, 0);
          }
        __syncthreads();
      }
    }
  }

  // epilogue: D row = (lane>>4)*4+q (m dim), col = lane&15 (co dim)
  #pragma unroll
  for (int j = 0; j < 2; ++j) {
    int co = nt * 64 + wn + j * 16 + l15;
    float bb = bias[co];
    #pragma unroll
    for (int i = 0; i < 4; ++i) {
      int m0 = mt * 128 + wm + i * 16 + l4 * 4;
      #pragma unroll
      for (int q = 0; q < 4; ++q) {
        int m = m0 + q;
        int b = m / 36, s = m - b * 36;
        Y[((size_t)b * 256 + co) * 36 + s] = acc[i][j][q] + bb;
      }
    }
  }
}

// ---------- squash (in place on d_out): groups of 8 consecutive floats ----------
__global__ __launch_bounds__(256) void squash_k(float* __restrict__ Y) {
  const int g = blockIdx.x * 256 + threadIdx.x;  // 0..589823
  float4* p = (float4*)(Y + (size_t)g * 8);
  float4 a = p[0], b = p[1];
  float ns = a.x * a.x + a.y * a.y + a.z * a.z + a.w * a.w +
             b.x * b.x + b.y * b.y + b.z * b.z + b.w * b.w;
  float sc = ns / ((1.0f + ns) * (0.001f + sqrtf(ns)));
  a.x *= sc; a.y *= sc; a.z *= sc; a.w *= sc;
  b.x *= sc; b.y *= sc; b.z *= sc; b.w *= sc;
  p[0] = a; p[1] = b;
}

extern "C" void kernel_launch(void* const* d_in, const int* in_sizes, int n_in,
                              void* d_out, int out_size, void* d_ws, size_t ws_size,
                              hipStream_t stream) {
  const float* X = (const float*)d_in[0];     // [512,256,20,20]
  const float* W = (const float*)d_in[1];     // [256,256,9,9]
  const float* bias = (const float*)d_in[2];  // [256]
  float* Y = (float*)d_out;                   // [512,256,6,6] -> squashed

  unsigned short* Xt = (unsigned short*)d_ws;                 // 512*400*256 bf16
  unsigned short* Wt = Xt + (size_t)512 * 400 * 256;          // 81*256*256 bf16

  xform_x<<<512, 256, 0, stream>>>(X, Xt);
  xform_w<<<dim3(256, 2), 256, 0, stream>>>(W, Wt);
  conv_gemm<<<dim3(144, 4), 256, 0, stream>>>(Xt, Wt, bias, Y);
  squash_k<<<2304, 256, 0, stream>>>(Y);
}